// Round 3
// baseline (242.077 us; speedup 1.0000x reference)
//
#include <hip/hip_runtime.h>
#include <hip/hip_bf16.h>
#include <hip/hip_fp8.h>
#include <stdint.h>

#define M_ROWS 8192
#define K_IN   2048
#define N_OUT  2048

typedef int   v4i   __attribute__((ext_vector_type(4)));
typedef int   v8i   __attribute__((ext_vector_type(8)));
typedef float f32x4 __attribute__((ext_vector_type(4)));

// ---------------------------------------------------------------------------
// async global->LDS, 16B per lane. LDS dest = wave-uniform base + lane*16.
__device__ __forceinline__ void load_lds16(const void* g, void* l) {
    __builtin_amdgcn_global_load_lds(
        (const __attribute__((address_space(1))) uint32_t*)g,
        (__attribute__((address_space(3))) uint32_t*)l,
        16, 0, 0);
}

// ---------------------------------------------------------------------------
// Quantization: ONE WAVE PER ROW, no LDS, no __syncthreads, fully coalesced.
// Waves [0, M_ROWS): input rows -> per-row absmax + sign(x) as fp8
//   (+1 -> 0x38, -1 -> 0xB8, 0 -> 0x00).
// Waves [M_ROWS, M_ROWS+N_OUT): weight rows -> sign(w)/gamma[k] as fp8 e4m3.
// Lane handles float4 number (j*64 + lane), j=0..7  (64*8*4 = 2048 elems).
__global__ __launch_bounds__(256) void quant_rows(
    const float* __restrict__ in, const float* __restrict__ w,
    const float* __restrict__ gamma,
    uint8_t* __restrict__ aq, uint8_t* __restrict__ wq,
    float* __restrict__ scale)
{
    const int lane = threadIdx.x & 63;
    const int wv   = threadIdx.x >> 6;
    const int gw   = blockIdx.x * 4 + wv;          // global wave id = row id

    if (gw < M_ROWS) {
        const float4* rp = (const float4*)(in + (size_t)gw * K_IN);
        uint32_t* op = (uint32_t*)(aq + (size_t)gw * K_IN);
        float m = 0.f;
        #pragma unroll
        for (int j = 0; j < 8; j++) {
            float4 x = rp[j * 64 + lane];
            float xs[4] = {x.x, x.y, x.z, x.w};
            uint32_t pk = 0;
            #pragma unroll
            for (int c = 0; c < 4; c++) {
                m = fmaxf(m, fabsf(xs[c]));
                uint32_t b = (xs[c] > 0.f) ? 0x38u : ((xs[c] < 0.f) ? 0xB8u : 0u);
                pk |= b << (8 * c);
            }
            op[j * 64 + lane] = pk;
        }
        #pragma unroll
        for (int off = 32; off > 0; off >>= 1) m = fmaxf(m, __shfl_down(m, off));
        if (lane == 0) scale[gw] = m;
    } else {
        const int r = gw - M_ROWS;
        const float4* rp = (const float4*)(w + (size_t)r * K_IN);
        const float4* gp = (const float4*)gamma;
        uint32_t* op = (uint32_t*)(wq + (size_t)r * K_IN);
        #pragma unroll
        for (int j = 0; j < 8; j++) {
            float4 x = rp[j * 64 + lane];
            float4 g = gp[j * 64 + lane];
            float xs[4] = {x.x, x.y, x.z, x.w};
            float gs[4] = {g.x, g.y, g.z, g.w};
            uint32_t pk = 0;
            #pragma unroll
            for (int c = 0; c < 4; c++) {
                float s = (xs[c] > 0.f) ? 1.f : ((xs[c] < 0.f) ? -1.f : 0.f);
                __hip_fp8_e4m3 f(s / gs[c]);
                pk |= ((uint32_t)f.__x) << (8 * c);
            }
            op[j * 64 + lane] = pk;
        }
    }
}

// ---------------------------------------------------------------------------
// MX-fp8 MFMA GEMM: C[m,n] = sum_k Aq[m,k]*Wq[n,k], both fp8 row-major
// (k contiguous). 128x128 block tile, BK=128 bytes, 4 waves each owning
// 64x64 via 4x4 grid of 16x16x128 scaled MFMAs with unit (0x7F) scales.
// LDS XOR swizzle: physical 16B chunk = logical chunk ^ (row & 7).
// __launch_bounds__(256,4): VGPR<=128 so 4 blocks/CU can be resident —
// cross-block overlap hides the vmcnt(0)+barrier drain (m114 mechanism).
#define BM  128
#define BN  128
#define BKB 128

__global__ __launch_bounds__(256, 4) void gemm_q(
    const uint8_t* __restrict__ Aq,
    const uint8_t* __restrict__ Wq,
    const float* __restrict__ scale,
    const float* __restrict__ bias,
    const float* __restrict__ beta,
    float* __restrict__ out)
{
    __shared__ uint8_t As[BM * BKB];   // 16 KB
    __shared__ uint8_t Bs[BN * BKB];   // 16 KB

    const int tid  = threadIdx.x;
    const int lane = tid & 63;
    const int wave = tid >> 6;

    const int row0 = blockIdx.x * BM;
    const int col0 = blockIdx.y * BN;

    const int wm = (wave >> 1) * 64;
    const int wn = (wave & 1)  * 64;

    // staging: thread t (issue i) covers LDS row i*32 + (t>>3), phys chunk t&7
    const int st_row = tid >> 3;                 // 0..31
    const int st_pc  = tid & 7;                  // physical 16B chunk
    const int st_gc  = st_pc ^ (st_row & 7);     // swizzled source chunk

    const uint8_t* gA = Aq + (size_t)(row0 + st_row) * K_IN + st_gc * 16;
    const uint8_t* gB = Wq + (size_t)(col0 + st_row) * K_IN + st_gc * 16;
    uint8_t* lA = &As[st_row * BKB + st_pc * 16];
    uint8_t* lB = &Bs[st_row * BKB + st_pc * 16];

    f32x4 acc[4][4];
    #pragma unroll
    for (int i = 0; i < 4; i++) {
        #pragma unroll
        for (int j = 0; j < 4; j++) acc[i][j] = (f32x4)(0.f);
    }

    const int fr = lane & 15;            // fragment row (m or n)
    const int g2 = (lane >> 4) * 2;      // first logical chunk of this k-group
    const int off0 = ((g2     ^ (fr & 7)) << 4);
    const int off1 = (((g2+1) ^ (fr & 7)) << 4);

    for (int k0 = 0; k0 < K_IN; k0 += BKB) {
        #pragma unroll
        for (int i = 0; i < 4; i++)
            load_lds16(gA + (size_t)(i * 32) * K_IN + k0, lA + i * 32 * BKB);
        #pragma unroll
        for (int i = 0; i < 4; i++)
            load_lds16(gB + (size_t)(i * 32) * K_IN + k0, lB + i * 32 * BKB);
        __syncthreads();

        v8i a[4], b[4];
        #pragma unroll
        for (int mi = 0; mi < 4; mi++) {
            const uint8_t* p = &As[(wm + mi * 16 + fr) * BKB];
            v4i lo = *(const v4i*)(p + off0);
            v4i hi = *(const v4i*)(p + off1);
            a[mi] = (v8i){lo.x, lo.y, lo.z, lo.w, hi.x, hi.y, hi.z, hi.w};
        }
        #pragma unroll
        for (int ni = 0; ni < 4; ni++) {
            const uint8_t* p = &Bs[(wn + ni * 16 + fr) * BKB];
            v4i lo = *(const v4i*)(p + off0);
            v4i hi = *(const v4i*)(p + off1);
            b[ni] = (v8i){lo.x, lo.y, lo.z, lo.w, hi.x, hi.y, hi.z, hi.w};
        }
        #pragma unroll
        for (int mi = 0; mi < 4; mi++) {
            #pragma unroll
            for (int ni = 0; ni < 4; ni++)
                acc[mi][ni] = __builtin_amdgcn_mfma_scale_f32_16x16x128_f8f6f4(
                    a[mi], b[ni], acc[mi][ni],
                    0 /*cbsz: A=fp8*/, 0 /*blgp: B=fp8*/,
                    0, 0x7F7F7F7F,   /* A scales = 1.0 */
                    0, 0x7F7F7F7F);  /* B scales = 1.0 */
        }
        __syncthreads();
    }

    // epilogue: C/D layout col=lane&15, row=(lane>>4)*4+reg
    const int ecol = lane & 15;
    const int erow = (lane >> 4) * 4;

    float bi[4], be[4];
    #pragma unroll
    for (int ni = 0; ni < 4; ni++) {
        int col = col0 + wn + ni * 16 + ecol;
        bi[ni] = bias[col];
        be[ni] = beta[col];
    }
    #pragma unroll
    for (int mi = 0; mi < 4; mi++) {
        int rbase = row0 + wm + mi * 16 + erow;
        float sc[4];
        #pragma unroll
        for (int r = 0; r < 4; r++) sc[r] = scale[rbase + r];
        #pragma unroll
        for (int ni = 0; ni < 4; ni++) {
            int col = col0 + wn + ni * 16 + ecol;
            float* op = out + (size_t)rbase * N_OUT + col;
            #pragma unroll
            for (int r = 0; r < 4; r++)
                op[(size_t)r * N_OUT] = (acc[mi][ni][r] * sc[r] + bi[ni]) * be[ni];
        }
    }
}

// ---------------------------------------------------------------------------
// Fallback (no workspace): correct but slow.
__global__ __launch_bounds__(256) void fallback_kernel(
    const float* __restrict__ in, const float* __restrict__ w,
    const float* __restrict__ bias, const float* __restrict__ gamma,
    const float* __restrict__ beta, float* __restrict__ out)
{
    __shared__ float s_sign[K_IN];
    __shared__ float sred[4];
    const int row = blockIdx.x;
    const int tid = threadIdx.x;
    float m = 0.f;
    for (int k = tid; k < K_IN; k += 256) {
        float x = in[(size_t)row * K_IN + k];
        m = fmaxf(m, fabsf(x));
        float s = (x > 0.f) ? 1.f : ((x < 0.f) ? -1.f : 0.f);
        s_sign[k] = s / gamma[k];
    }
    #pragma unroll
    for (int off = 32; off > 0; off >>= 1) m = fmaxf(m, __shfl_down(m, off));
    if ((tid & 63) == 0) sred[tid >> 6] = m;
    __syncthreads();
    float qs = fmaxf(fmaxf(sred[0], sred[1]), fmaxf(sred[2], sred[3]));
    for (int o = tid; o < N_OUT; o += 256) {
        const float* wr = w + (size_t)o * K_IN;
        float acc2 = 0.f;
        for (int k = 0; k < K_IN; k++) {
            float wv = wr[k];
            float ws_ = (wv > 0.f) ? 1.f : ((wv < 0.f) ? -1.f : 0.f);
            acc2 += s_sign[k] * ws_;
        }
        out[(size_t)row * N_OUT + o] = (acc2 * qs + bias[o]) * beta[o];
    }
}

// ---------------------------------------------------------------------------
extern "C" void kernel_launch(void* const* d_in, const int* in_sizes, int n_in,
                              void* d_out, int out_size, void* d_ws, size_t ws_size,
                              hipStream_t stream) {
    const float* input  = (const float*)d_in[0];
    const float* weight = (const float*)d_in[1];
    const float* bias   = (const float*)d_in[2];
    const float* gamma  = (const float*)d_in[3];
    const float* beta   = (const float*)d_in[4];
    float* out = (float*)d_out;

    const size_t aq_bytes = (size_t)M_ROWS * K_IN;            // 16 MB
    const size_t wq_bytes = (size_t)N_OUT * K_IN;             //  4 MB
    const size_t sc_bytes = (size_t)M_ROWS * sizeof(float);   // 32 KB

    if (ws_size >= aq_bytes + wq_bytes + sc_bytes) {
        uint8_t* aq    = (uint8_t*)d_ws;
        uint8_t* wq    = (uint8_t*)d_ws + aq_bytes;
        float*   scale = (float*)((char*)d_ws + aq_bytes + wq_bytes);

        const int q_blocks = (M_ROWS + N_OUT) / 4;            // 2560 (4 waves/blk)
        quant_rows<<<q_blocks, 256, 0, stream>>>(
            input, weight, gamma, aq, wq, scale);
        dim3 grid(M_ROWS / BM, N_OUT / BN);
        gemm_q<<<grid, 256, 0, stream>>>(aq, wq, scale, bias, beta, out);
    } else {
        fallback_kernel<<<M_ROWS, 256, 0, stream>>>(input, weight, bias, gamma, beta, out);
    }
}

// Round 4
// 169.919 us; speedup vs baseline: 1.4247x; 1.4247x over previous
//
#include <hip/hip_runtime.h>
#include <hip/hip_bf16.h>
#include <hip/hip_fp8.h>
#include <stdint.h>

#define M_ROWS 8192
#define K_IN   2048
#define N_OUT  2048

typedef int   v4i   __attribute__((ext_vector_type(4)));
typedef int   v8i   __attribute__((ext_vector_type(8)));
typedef float f32x4 __attribute__((ext_vector_type(4)));

// ---------------------------------------------------------------------------
// Quantization: one wave per row, no LDS, no barriers, fully coalesced.
// Waves [0, M_ROWS): input rows -> per-row absmax + sign(x) as fp8
//   (+1 -> 0x38, -1 -> 0xB8, 0 -> 0x00).
// Waves [M_ROWS, M_ROWS+N_OUT): weight rows -> sign(w)/gamma[k] as fp8 e4m3.
__global__ __launch_bounds__(256) void quant_rows(
    const float* __restrict__ in, const float* __restrict__ w,
    const float* __restrict__ gamma,
    uint8_t* __restrict__ aq, uint8_t* __restrict__ wq,
    float* __restrict__ scale)
{
    const int lane = threadIdx.x & 63;
    const int wv   = threadIdx.x >> 6;
    const int gw   = blockIdx.x * 4 + wv;          // global wave id = row id

    if (gw < M_ROWS) {
        const float4* rp = (const float4*)(in + (size_t)gw * K_IN);
        uint32_t* op = (uint32_t*)(aq + (size_t)gw * K_IN);
        float m = 0.f;
        #pragma unroll
        for (int j = 0; j < 8; j++) {
            float4 x = rp[j * 64 + lane];
            float xs[4] = {x.x, x.y, x.z, x.w};
            uint32_t pk = 0;
            #pragma unroll
            for (int c = 0; c < 4; c++) {
                m = fmaxf(m, fabsf(xs[c]));
                uint32_t b = (xs[c] > 0.f) ? 0x38u : ((xs[c] < 0.f) ? 0xB8u : 0u);
                pk |= b << (8 * c);
            }
            op[j * 64 + lane] = pk;
        }
        #pragma unroll
        for (int off = 32; off > 0; off >>= 1) m = fmaxf(m, __shfl_down(m, off));
        if (lane == 0) scale[gw] = m;
    } else {
        const int r = gw - M_ROWS;
        const float4* rp = (const float4*)(w + (size_t)r * K_IN);
        const float4* gp = (const float4*)gamma;
        uint32_t* op = (uint32_t*)(wq + (size_t)r * K_IN);
        #pragma unroll
        for (int j = 0; j < 8; j++) {
            float4 x = rp[j * 64 + lane];
            float4 g = gp[j * 64 + lane];
            float xs[4] = {x.x, x.y, x.z, x.w};
            float gs[4] = {g.x, g.y, g.z, g.w};
            uint32_t pk = 0;
            #pragma unroll
            for (int c = 0; c < 4; c++) {
                float s = (xs[c] > 0.f) ? 1.f : ((xs[c] < 0.f) ? -1.f : 0.f);
                __hip_fp8_e4m3 f(s / gs[c]);
                pk |= ((uint32_t)f.__x) << (8 * c);
            }
            op[j * 64 + lane] = pk;
        }
    }
}

// ---------------------------------------------------------------------------
// MX-fp8 MFMA GEMM with REGISTER-STAGED DOUBLE BUFFERING.
// C[m,n] = sum_k Aq[m,k]*Wq[n,k], both fp8 row-major (k contiguous).
// 128x128 block tile, BK=128 bytes, 4 waves each owning 64x64 via 4x4 grid
// of 16x16x128 scaled MFMAs with unit (0x7F) scales.
// K-loop: global_load_dwordx4 tile k+1 -> regs, compute tile k from LDS,
// barrier, ds_write regs -> LDS, barrier. The vmcnt wait for the staged
// loads lands after the compute window — HBM/L2 latency hidden (the
// overlap the global_load_lds+barrier structure cannot express).
// LDS XOR swizzle: physical 16B chunk = logical chunk ^ (row & 7).
// NOTE: do NOT raise min-waves in launch_bounds — (256,4) capped VGPR at 64
// and spilled acc to scratch (WRITE_SIZE 65->324 MB, 2.5x slower).
#define BM  128
#define BN  128
#define BKB 128

__global__ __launch_bounds__(256, 2) void gemm_q(
    const uint8_t* __restrict__ Aq,
    const uint8_t* __restrict__ Wq,
    const float* __restrict__ scale,
    const float* __restrict__ bias,
    const float* __restrict__ beta,
    float* __restrict__ out)
{
    __shared__ uint8_t As[BM * BKB];   // 16 KB
    __shared__ uint8_t Bs[BN * BKB];   // 16 KB

    const int tid  = threadIdx.x;
    const int lane = tid & 63;
    const int wave = tid >> 6;

    const int row0 = blockIdx.x * BM;
    const int col0 = blockIdx.y * BN;

    const int wm = (wave >> 1) * 64;
    const int wn = (wave & 1)  * 64;

    // staging: thread t (issue i) covers row i*32 + (t>>3), phys chunk t&7
    const int st_row = tid >> 3;                 // 0..31
    const int st_pc  = tid & 7;                  // physical 16B chunk
    const int st_gc  = st_pc ^ (st_row & 7);     // swizzled source chunk

    const uint8_t* gA = Aq + (size_t)(row0 + st_row) * K_IN + st_gc * 16;
    const uint8_t* gB = Wq + (size_t)(col0 + st_row) * K_IN + st_gc * 16;
    uint8_t* lA = &As[st_row * BKB + st_pc * 16];
    uint8_t* lB = &Bs[st_row * BKB + st_pc * 16];

    f32x4 acc[4][4];
    #pragma unroll
    for (int i = 0; i < 4; i++) {
        #pragma unroll
        for (int j = 0; j < 4; j++) acc[i][j] = (f32x4)(0.f);
    }

    const int fr = lane & 15;            // fragment row (m or n)
    const int g2 = (lane >> 4) * 2;      // first logical chunk of this k-group
    const int off0 = ((g2     ^ (fr & 7)) << 4);
    const int off1 = (((g2+1) ^ (fr & 7)) << 4);

    v4i ra[4], rb[4];

    // prologue: stage tile 0
    #pragma unroll
    for (int i = 0; i < 4; i++) {
        ra[i] = *(const v4i*)(gA + (size_t)(i * 32) * K_IN);
        rb[i] = *(const v4i*)(gB + (size_t)(i * 32) * K_IN);
    }
    #pragma unroll
    for (int i = 0; i < 4; i++) {
        *(v4i*)(lA + i * 32 * BKB) = ra[i];
        *(v4i*)(lB + i * 32 * BKB) = rb[i];
    }
    __syncthreads();

    for (int k0 = 0; k0 < K_IN; k0 += BKB) {
        const bool pf = (k0 + BKB) < K_IN;
        if (pf) {
            #pragma unroll
            for (int i = 0; i < 4; i++) {
                ra[i] = *(const v4i*)(gA + (size_t)(i * 32) * K_IN + k0 + BKB);
                rb[i] = *(const v4i*)(gB + (size_t)(i * 32) * K_IN + k0 + BKB);
            }
        }

        v8i a[4], b[4];
        #pragma unroll
        for (int mi = 0; mi < 4; mi++) {
            const uint8_t* p = &As[(wm + mi * 16 + fr) * BKB];
            v4i lo = *(const v4i*)(p + off0);
            v4i hi = *(const v4i*)(p + off1);
            a[mi] = (v8i){lo.x, lo.y, lo.z, lo.w, hi.x, hi.y, hi.z, hi.w};
        }
        #pragma unroll
        for (int ni = 0; ni < 4; ni++) {
            const uint8_t* p = &Bs[(wn + ni * 16 + fr) * BKB];
            v4i lo = *(const v4i*)(p + off0);
            v4i hi = *(const v4i*)(p + off1);
            b[ni] = (v8i){lo.x, lo.y, lo.z, lo.w, hi.x, hi.y, hi.z, hi.w};
        }
        #pragma unroll
        for (int mi = 0; mi < 4; mi++) {
            #pragma unroll
            for (int ni = 0; ni < 4; ni++)
                acc[mi][ni] = __builtin_amdgcn_mfma_scale_f32_16x16x128_f8f6f4(
                    a[mi], b[ni], acc[mi][ni],
                    0 /*cbsz: A=fp8*/, 0 /*blgp: B=fp8*/,
                    0, 0x7F7F7F7F,   /* A scales = 1.0 */
                    0, 0x7F7F7F7F);  /* B scales = 1.0 */
        }
        __syncthreads();
        if (pf) {
            #pragma unroll
            for (int i = 0; i < 4; i++) {
                *(v4i*)(lA + i * 32 * BKB) = ra[i];
                *(v4i*)(lB + i * 32 * BKB) = rb[i];
            }
            __syncthreads();
        }
    }

    // epilogue: C/D layout col=lane&15, row=(lane>>4)*4+reg
    const int ecol = lane & 15;
    const int erow = (lane >> 4) * 4;

    float bi[4], be[4];
    #pragma unroll
    for (int ni = 0; ni < 4; ni++) {
        int col = col0 + wn + ni * 16 + ecol;
        bi[ni] = bias[col];
        be[ni] = beta[col];
    }
    #pragma unroll
    for (int mi = 0; mi < 4; mi++) {
        int rbase = row0 + wm + mi * 16 + erow;
        float sc[4];
        #pragma unroll
        for (int r = 0; r < 4; r++) sc[r] = scale[rbase + r];
        #pragma unroll
        for (int ni = 0; ni < 4; ni++) {
            int col = col0 + wn + ni * 16 + ecol;
            float* op = out + (size_t)rbase * N_OUT + col;
            #pragma unroll
            for (int r = 0; r < 4; r++)
                op[(size_t)r * N_OUT] = (acc[mi][ni][r] * sc[r] + bi[ni]) * be[ni];
        }
    }
}

// ---------------------------------------------------------------------------
// Fallback (no workspace): correct but slow.
__global__ __launch_bounds__(256) void fallback_kernel(
    const float* __restrict__ in, const float* __restrict__ w,
    const float* __restrict__ bias, const float* __restrict__ gamma,
    const float* __restrict__ beta, float* __restrict__ out)
{
    __shared__ float s_sign[K_IN];
    __shared__ float sred[4];
    const int row = blockIdx.x;
    const int tid = threadIdx.x;
    float m = 0.f;
    for (int k = tid; k < K_IN; k += 256) {
        float x = in[(size_t)row * K_IN + k];
        m = fmaxf(m, fabsf(x));
        float s = (x > 0.f) ? 1.f : ((x < 0.f) ? -1.f : 0.f);
        s_sign[k] = s / gamma[k];
    }
    #pragma unroll
    for (int off = 32; off > 0; off >>= 1) m = fmaxf(m, __shfl_down(m, off));
    if ((tid & 63) == 0) sred[tid >> 6] = m;
    __syncthreads();
    float qs = fmaxf(fmaxf(sred[0], sred[1]), fmaxf(sred[2], sred[3]));
    for (int o = tid; o < N_OUT; o += 256) {
        const float* wr = w + (size_t)o * K_IN;
        float acc2 = 0.f;
        for (int k = 0; k < K_IN; k++) {
            float wv = wr[k];
            float ws_ = (wv > 0.f) ? 1.f : ((wv < 0.f) ? -1.f : 0.f);
            acc2 += s_sign[k] * ws_;
        }
        out[(size_t)row * N_OUT + o] = (acc2 * qs + bias[o]) * beta[o];
    }
}

// ---------------------------------------------------------------------------
extern "C" void kernel_launch(void* const* d_in, const int* in_sizes, int n_in,
                              void* d_out, int out_size, void* d_ws, size_t ws_size,
                              hipStream_t stream) {
    const float* input  = (const float*)d_in[0];
    const float* weight = (const float*)d_in[1];
    const float* bias   = (const float*)d_in[2];
    const float* gamma  = (const float*)d_in[3];
    const float* beta   = (const float*)d_in[4];
    float* out = (float*)d_out;

    const size_t aq_bytes = (size_t)M_ROWS * K_IN;            // 16 MB
    const size_t wq_bytes = (size_t)N_OUT * K_IN;             //  4 MB
    const size_t sc_bytes = (size_t)M_ROWS * sizeof(float);   // 32 KB

    if (ws_size >= aq_bytes + wq_bytes + sc_bytes) {
        uint8_t* aq    = (uint8_t*)d_ws;
        uint8_t* wq    = (uint8_t*)d_ws + aq_bytes;
        float*   scale = (float*)((char*)d_ws + aq_bytes + wq_bytes);

        const int q_blocks = (M_ROWS + N_OUT) / 4;            // 2560 (4 waves/blk)
        quant_rows<<<q_blocks, 256, 0, stream>>>(
            input, weight, gamma, aq, wq, scale);
        dim3 grid(M_ROWS / BM, N_OUT / BN);
        gemm_q<<<grid, 256, 0, stream>>>(aq, wq, scale, bias, beta, out);
    } else {
        fallback_kernel<<<M_ROWS, 256, 0, stream>>>(input, weight, bias, gamma, beta, out);
    }
}

// Round 5
// 152.267 us; speedup vs baseline: 1.5898x; 1.1159x over previous
//
#include <hip/hip_runtime.h>
#include <hip/hip_bf16.h>
#include <stdint.h>

#define M_ROWS 8192
#define K_IN   2048
#define KB4    (K_IN / 2)          // packed fp4 bytes per row = 1024
#define N_OUT  2048

typedef int   v4i   __attribute__((ext_vector_type(4)));
typedef int   v8i   __attribute__((ext_vector_type(8)));
typedef float f32x4 __attribute__((ext_vector_type(4)));

// ---------------------------------------------------------------------------
// async global->LDS, 16B per lane. LDS dest = wave-uniform base + lane*16.
__device__ __forceinline__ void load_lds16(const void* g, void* l) {
    __builtin_amdgcn_global_load_lds(
        (const __attribute__((address_space(1))) uint32_t*)g,
        (__attribute__((address_space(3))) uint32_t*)l,
        16, 0, 0);
}

// fp4 e2m1 RNE quantization of v. Levels: 0,0.5,1,1.5,2,3,4,6.
__device__ __forceinline__ uint32_t fp4_e2m1(float v) {
    float m = fabsf(v);
    uint32_t s = (v < 0.f) ? 0x8u : 0x0u;
    uint32_t c;
    if      (m < 0.25f) c = 0;
    else if (m < 0.75f) c = 1;
    else if (m < 1.25f) c = 2;
    else if (m < 1.75f) c = 3;
    else if (m < 2.50f) c = 4;
    else if (m < 3.50f) c = 5;
    else if (m < 5.00f) c = 6;
    else                c = 7;
    return (c == 0) ? 0u : (s | c);
}

// ---------------------------------------------------------------------------
// Quantization to packed fp4: one wave per row, coalesced, no barriers.
// Waves [0, M_ROWS): input rows -> per-row absmax + sign(x) as fp4
//   (+1 -> 0x2, -1 -> 0xA, 0 -> 0x0), elem 2i in low nibble.
// Waves [M_ROWS, M_ROWS+N_OUT): weight rows -> e2m1(sign(w)/gamma[k]).
// Lane L, step j: float4 at index j*64+L -> 4 nibbles -> u16 at j*64+L.
__global__ __launch_bounds__(256) void quant_rows(
    const float* __restrict__ in, const float* __restrict__ w,
    const float* __restrict__ gamma,
    uint8_t* __restrict__ aq, uint8_t* __restrict__ wq,
    float* __restrict__ scale)
{
    const int lane = threadIdx.x & 63;
    const int wv   = threadIdx.x >> 6;
    const int gw   = blockIdx.x * 4 + wv;          // global wave id = row id

    if (gw < M_ROWS) {
        const float4* rp = (const float4*)(in + (size_t)gw * K_IN);
        uint16_t* op = (uint16_t*)(aq + (size_t)gw * KB4);
        float m = 0.f;
        #pragma unroll
        for (int j = 0; j < 8; j++) {
            float4 x = rp[j * 64 + lane];
            float xs[4] = {x.x, x.y, x.z, x.w};
            uint32_t pk = 0;
            #pragma unroll
            for (int c = 0; c < 4; c++) {
                m = fmaxf(m, fabsf(xs[c]));
                uint32_t n = (xs[c] > 0.f) ? 0x2u : ((xs[c] < 0.f) ? 0xAu : 0u);
                pk |= n << (4 * c);
            }
            op[j * 64 + lane] = (uint16_t)pk;
        }
        #pragma unroll
        for (int off = 32; off > 0; off >>= 1) m = fmaxf(m, __shfl_down(m, off));
        if (lane == 0) scale[gw] = m;
    } else {
        const int r = gw - M_ROWS;
        const float4* rp = (const float4*)(w + (size_t)r * K_IN);
        const float4* gp = (const float4*)gamma;
        uint16_t* op = (uint16_t*)(wq + (size_t)r * KB4);
        #pragma unroll
        for (int j = 0; j < 8; j++) {
            float4 x = rp[j * 64 + lane];
            float4 g = gp[j * 64 + lane];
            float xs[4] = {x.x, x.y, x.z, x.w};
            float gs[4] = {g.x, g.y, g.z, g.w};
            uint32_t pk = 0;
            #pragma unroll
            for (int c = 0; c < 4; c++) {
                float s = (xs[c] > 0.f) ? 1.f : ((xs[c] < 0.f) ? -1.f : 0.f);
                pk |= fp4_e2m1(s / gs[c]) << (4 * c);
            }
            op[j * 64 + lane] = (uint16_t)pk;
        }
    }
}

// ---------------------------------------------------------------------------
// MX-fp4 MFMA GEMM: C[m,n] = sum_k Aq[m,k]*Wq[n,k], both packed fp4
// row-major (k contiguous, elem 2i low nibble). 128x128 block tile,
// BK=256 elems (128 B/row/iter), 8 K-iters. 4 waves own 64x64 each via
// 4x4 grid of 16x16x128 fp4-scaled MFMAs (cbsz=blgp=4), 2 per k-iter.
// DMA staging (global_load_lds x16B) + XOR chunk swizzle
// (phys chunk = logical chunk ^ (row & 7)) — source-side swizzle keeps
// LDS dest lane-contiguous. NOTE: (256,4) caps VGPR at 64 and spills acc
// (WRITE 65->324 MB, 2.5x slower — round 3); register-staged dbuf loses
// on LDS-port pressure (round 4). Keep (256,2) + DMA.
#define BM   128
#define BN   128
#define BKBY 128   /* bytes of packed fp4 per row per iter = 256 elems */

__global__ __launch_bounds__(256, 2) void gemm_q(
    const uint8_t* __restrict__ Aq,
    const uint8_t* __restrict__ Wq,
    const float* __restrict__ scale,
    const float* __restrict__ bias,
    const float* __restrict__ beta,
    float* __restrict__ out)
{
    __shared__ uint8_t As[BM * BKBY];   // 16 KB
    __shared__ uint8_t Bs[BN * BKBY];   // 16 KB

    const int tid  = threadIdx.x;
    const int lane = tid & 63;
    const int wave = tid >> 6;

    const int row0 = blockIdx.x * BM;
    const int col0 = blockIdx.y * BN;

    const int wm = (wave >> 1) * 64;
    const int wn = (wave & 1)  * 64;

    // staging: thread t (issue i) covers row i*32 + (t>>3), phys chunk t&7
    const int st_row = tid >> 3;                 // 0..31
    const int st_pc  = tid & 7;                  // physical 16B chunk
    const int st_gc  = st_pc ^ (st_row & 7);     // swizzled source chunk

    const uint8_t* gA = Aq + (size_t)(row0 + st_row) * KB4 + st_gc * 16;
    const uint8_t* gB = Wq + (size_t)(col0 + st_row) * KB4 + st_gc * 16;
    uint8_t* lA = &As[st_row * BKBY + st_pc * 16];
    uint8_t* lB = &Bs[st_row * BKBY + st_pc * 16];

    f32x4 acc[4][4];
    #pragma unroll
    for (int i = 0; i < 4; i++) {
        #pragma unroll
        for (int j = 0; j < 4; j++) acc[i][j] = (f32x4)(0.f);
    }

    const int fr = lane & 15;            // fragment row (m or n)
    const int g  = lane >> 4;            // k-chunk group (32 elems = 16 B)
    // chunk for kh-th half-row (kh*4+g), XOR-swizzled per row
    const int off0 = ((0 * 4 + g) ^ (fr & 7)) << 4;
    const int off1 = ((1 * 4 + g) ^ (fr & 7)) << 4;

    for (int kb = 0; kb < KB4; kb += BKBY) {
        #pragma unroll
        for (int i = 0; i < 4; i++)
            load_lds16(gA + (size_t)(i * 32) * KB4 + kb, lA + i * 32 * BKBY);
        #pragma unroll
        for (int i = 0; i < 4; i++)
            load_lds16(gB + (size_t)(i * 32) * KB4 + kb, lB + i * 32 * BKBY);
        __syncthreads();

        #pragma unroll
        for (int kh = 0; kh < 2; kh++) {
            const int off = kh ? off1 : off0;
            v8i a[4], b[4];
            #pragma unroll
            for (int mi = 0; mi < 4; mi++) {
                v4i lo = *(const v4i*)(&As[(wm + mi * 16 + fr) * BKBY] + off);
                a[mi] = (v8i){lo.x, lo.y, lo.z, lo.w, 0, 0, 0, 0};
            }
            #pragma unroll
            for (int ni = 0; ni < 4; ni++) {
                v4i lo = *(const v4i*)(&Bs[(wn + ni * 16 + fr) * BKBY] + off);
                b[ni] = (v8i){lo.x, lo.y, lo.z, lo.w, 0, 0, 0, 0};
            }
            #pragma unroll
            for (int mi = 0; mi < 4; mi++) {
                #pragma unroll
                for (int ni = 0; ni < 4; ni++)
                    acc[mi][ni] = __builtin_amdgcn_mfma_scale_f32_16x16x128_f8f6f4(
                        a[mi], b[ni], acc[mi][ni],
                        4 /*cbsz: A=fp4 e2m1*/, 4 /*blgp: B=fp4 e2m1*/,
                        0, 0x7F7F7F7F,   /* A scales = 1.0 */
                        0, 0x7F7F7F7F);  /* B scales = 1.0 */
            }
        }
        __syncthreads();
    }

    // epilogue: C/D layout col=lane&15, row=(lane>>4)*4+reg
    const int ecol = lane & 15;
    const int erow = (lane >> 4) * 4;

    float bi[4], be[4];
    #pragma unroll
    for (int ni = 0; ni < 4; ni++) {
        int col = col0 + wn + ni * 16 + ecol;
        bi[ni] = bias[col];
        be[ni] = beta[col];
    }
    #pragma unroll
    for (int mi = 0; mi < 4; mi++) {
        int rbase = row0 + wm + mi * 16 + erow;
        float sc[4];
        #pragma unroll
        for (int r = 0; r < 4; r++) sc[r] = scale[rbase + r];
        #pragma unroll
        for (int ni = 0; ni < 4; ni++) {
            int col = col0 + wn + ni * 16 + ecol;
            float* op = out + (size_t)rbase * N_OUT + col;
            #pragma unroll
            for (int r = 0; r < 4; r++)
                op[(size_t)r * N_OUT] = (acc[mi][ni][r] * sc[r] + bi[ni]) * be[ni];
        }
    }
}

// ---------------------------------------------------------------------------
// Fallback (no workspace): correct but slow.
__global__ __launch_bounds__(256) void fallback_kernel(
    const float* __restrict__ in, const float* __restrict__ w,
    const float* __restrict__ bias, const float* __restrict__ gamma,
    const float* __restrict__ beta, float* __restrict__ out)
{
    __shared__ float s_sign[K_IN];
    __shared__ float sred[4];
    const int row = blockIdx.x;
    const int tid = threadIdx.x;
    float m = 0.f;
    for (int k = tid; k < K_IN; k += 256) {
        float x = in[(size_t)row * K_IN + k];
        m = fmaxf(m, fabsf(x));
        float s = (x > 0.f) ? 1.f : ((x < 0.f) ? -1.f : 0.f);
        s_sign[k] = s / gamma[k];
    }
    #pragma unroll
    for (int off = 32; off > 0; off >>= 1) m = fmaxf(m, __shfl_down(m, off));
    if ((tid & 63) == 0) sred[tid >> 6] = m;
    __syncthreads();
    float qs = fmaxf(fmaxf(sred[0], sred[1]), fmaxf(sred[2], sred[3]));
    for (int o = tid; o < N_OUT; o += 256) {
        const float* wr = w + (size_t)o * K_IN;
        float acc2 = 0.f;
        for (int k = 0; k < K_IN; k++) {
            float wv = wr[k];
            float ws_ = (wv > 0.f) ? 1.f : ((wv < 0.f) ? -1.f : 0.f);
            acc2 += s_sign[k] * ws_;
        }
        out[(size_t)row * N_OUT + o] = (acc2 * qs + bias[o]) * beta[o];
    }
}

// ---------------------------------------------------------------------------
extern "C" void kernel_launch(void* const* d_in, const int* in_sizes, int n_in,
                              void* d_out, int out_size, void* d_ws, size_t ws_size,
                              hipStream_t stream) {
    const float* input  = (const float*)d_in[0];
    const float* weight = (const float*)d_in[1];
    const float* bias   = (const float*)d_in[2];
    const float* gamma  = (const float*)d_in[3];
    const float* beta   = (const float*)d_in[4];
    float* out = (float*)d_out;

    const size_t aq_bytes = (size_t)M_ROWS * KB4;             // 8 MB
    const size_t wq_bytes = (size_t)N_OUT * KB4;              // 2 MB
    const size_t sc_bytes = (size_t)M_ROWS * sizeof(float);   // 32 KB

    if (ws_size >= aq_bytes + wq_bytes + sc_bytes) {
        uint8_t* aq    = (uint8_t*)d_ws;
        uint8_t* wq    = (uint8_t*)d_ws + aq_bytes;
        float*   scale = (float*)((char*)d_ws + aq_bytes + wq_bytes);

        const int q_blocks = (M_ROWS + N_OUT) / 4;            // 2560 (4 waves/blk)
        quant_rows<<<q_blocks, 256, 0, stream>>>(
            input, weight, gamma, aq, wq, scale);
        dim3 grid(M_ROWS / BM, N_OUT / BN);
        gemm_q<<<grid, 256, 0, stream>>>(aq, wq, scale, bias, beta, out);
    } else {
        fallback_kernel<<<M_ROWS, 256, 0, stream>>>(input, weight, bias, gamma, beta, out);
    }
}

// Round 6
// 151.990 us; speedup vs baseline: 1.5927x; 1.0018x over previous
//
#include <hip/hip_runtime.h>
#include <hip/hip_bf16.h>
#include <stdint.h>

#define M_ROWS 8192
#define K_IN   2048
#define KB4    (K_IN / 2)          // packed fp4 bytes per row = 1024
#define N_OUT  2048

typedef int   v4i   __attribute__((ext_vector_type(4)));
typedef int   v8i   __attribute__((ext_vector_type(8)));
typedef float f32x4 __attribute__((ext_vector_type(4)));

// ---------------------------------------------------------------------------
// async global->LDS, 16B per lane. LDS dest = wave-uniform base + lane*16.
__device__ __forceinline__ void load_lds16(const void* g, void* l) {
    __builtin_amdgcn_global_load_lds(
        (const __attribute__((address_space(1))) uint32_t*)g,
        (__attribute__((address_space(3))) uint32_t*)l,
        16, 0, 0);
}

// fp4 e2m1 RNE quantization of v. Levels: 0,0.5,1,1.5,2,3,4,6.
__device__ __forceinline__ uint32_t fp4_e2m1(float v) {
    float m = fabsf(v);
    uint32_t s = (v < 0.f) ? 0x8u : 0x0u;
    uint32_t c;
    if      (m < 0.25f) c = 0;
    else if (m < 0.75f) c = 1;
    else if (m < 1.25f) c = 2;
    else if (m < 1.75f) c = 3;
    else if (m < 2.50f) c = 4;
    else if (m < 3.50f) c = 5;
    else if (m < 5.00f) c = 6;
    else                c = 7;
    return (c == 0) ? 0u : (s | c);
}

// ---------------------------------------------------------------------------
// Quantization. One wave per row, no barriers.
// Waves [0, M_ROWS): input rows -> per-row absmax + sign(x) as packed fp4,
//   ROW-MAJOR Aq[m][KB4] (+1 -> 0x2, -1 -> 0xA, 0 -> 0x0, elem 2i low nib).
// Waves [M_ROWS, +N_OUT): weight rows -> e2m1(sign(w)/gamma) written
//   CHUNK-TRANSPOSED: Wqt[c][n][16B], c = k/32 (lane L handles chunk L).
__global__ __launch_bounds__(256) void quant_rows(
    const float* __restrict__ in, const float* __restrict__ w,
    const float* __restrict__ gamma,
    uint8_t* __restrict__ aq, uint8_t* __restrict__ wqt,
    float* __restrict__ scale)
{
    const int lane = threadIdx.x & 63;
    const int wv   = threadIdx.x >> 6;
    const int gw   = blockIdx.x * 4 + wv;          // global wave id = row id

    if (gw < M_ROWS) {
        const float4* rp = (const float4*)(in + (size_t)gw * K_IN);
        uint16_t* op = (uint16_t*)(aq + (size_t)gw * KB4);
        float m = 0.f;
        #pragma unroll
        for (int j = 0; j < 8; j++) {
            float4 x = rp[j * 64 + lane];
            float xs[4] = {x.x, x.y, x.z, x.w};
            uint32_t pk = 0;
            #pragma unroll
            for (int c = 0; c < 4; c++) {
                m = fmaxf(m, fabsf(xs[c]));
                uint32_t n = (xs[c] > 0.f) ? 0x2u : ((xs[c] < 0.f) ? 0xAu : 0u);
                pk |= n << (4 * c);
            }
            op[j * 64 + lane] = (uint16_t)pk;
        }
        #pragma unroll
        for (int off = 32; off > 0; off >>= 1) m = fmaxf(m, __shfl_down(m, off));
        if (lane == 0) scale[gw] = m;
    } else {
        const int r = gw - M_ROWS;
        // lane L quantizes elems [L*32, L*32+32) of row r -> one 16B chunk
        const float4* rp = (const float4*)(w + (size_t)r * K_IN + lane * 32);
        const float4* gp = (const float4*)(gamma + lane * 32);
        uint32_t pk[4] = {0, 0, 0, 0};
        #pragma unroll
        for (int j = 0; j < 8; j++) {
            float4 x = rp[j];
            float4 g = gp[j];
            float xs[4] = {x.x, x.y, x.z, x.w};
            float gs[4] = {g.x, g.y, g.z, g.w};
            #pragma unroll
            for (int c = 0; c < 4; c++) {
                int e = j * 4 + c;                 // elem index within chunk
                float s = (xs[c] > 0.f) ? 1.f : ((xs[c] < 0.f) ? -1.f : 0.f);
                pk[e >> 3] |= fp4_e2m1(s / gs[c]) << ((e & 7) * 4);
            }
        }
        uint4 v; v.x = pk[0]; v.y = pk[1]; v.z = pk[2]; v.w = pk[3];
        *(uint4*)(wqt + ((size_t)lane * N_OUT + r) * 16) = v;
    }
}

// ---------------------------------------------------------------------------
// MX-fp4 MFMA GEMM, B DIRECT FROM GLOBAL (L2-resident, chunk-transposed).
// C[m,n] = sum_k Aq[m,k]*Wqt[k,n]. 128x128 block tile, BK=256 elems
// (128 B of A per row per iter), 8 K-iters. 4 waves own 64x64 each via
// 4x4 grid of 16x16x128 fp4-scaled MFMAs (cbsz=blgp=4), 2 per k-iter.
// A: DMA-staged to LDS with XOR chunk swizzle (phys = logical ^ (row&7)).
// B: coalesced global_load_dwordx4 per fragment (16 lanes -> 256 B
//    contiguous), no LDS, no barrier coupling -> compiler pipelines via
//    vmcnt. Wqt = 2 MB, fits per-XCD L2.
// NOTE: (256,4) caps VGPR at 64 and spills acc (R3, 2.5x slower);
// register-staged LDS dbuf loses on LDS-port pressure (R4). Keep (256,2).
#define BM   128
#define BN   128
#define BKBY 128   /* bytes of packed fp4 A per row per iter = 256 elems */

__global__ __launch_bounds__(256, 2) void gemm_q(
    const uint8_t* __restrict__ Aq,
    const uint8_t* __restrict__ Wqt,
    const float* __restrict__ scale,
    const float* __restrict__ bias,
    const float* __restrict__ beta,
    float* __restrict__ out)
{
    __shared__ uint8_t As[BM * BKBY];   // 16 KB (Bs eliminated)

    const int tid  = threadIdx.x;
    const int lane = tid & 63;
    const int wave = tid >> 6;

    const int row0 = blockIdx.x * BM;
    const int col0 = blockIdx.y * BN;

    const int wm = (wave >> 1) * 64;
    const int wn = (wave & 1)  * 64;

    // A staging: thread t (issue i) covers row i*32 + (t>>3), phys chunk t&7
    const int st_row = tid >> 3;                 // 0..31
    const int st_pc  = tid & 7;                  // physical 16B chunk
    const int st_gc  = st_pc ^ (st_row & 7);     // swizzled source chunk

    const uint8_t* gA = Aq + (size_t)(row0 + st_row) * KB4 + st_gc * 16;
    uint8_t* lA = &As[st_row * BKBY + st_pc * 16];

    f32x4 acc[4][4];
    #pragma unroll
    for (int i = 0; i < 4; i++) {
        #pragma unroll
        for (int j = 0; j < 4; j++) acc[i][j] = (f32x4)(0.f);
    }

    const int fr = lane & 15;            // fragment row (m) / col (n)
    const int g  = lane >> 4;            // k-chunk group (32 elems = 16 B)
    // A chunk offsets for kh-th half (chunk kh*4+g), XOR-swizzled per row
    const int offA0 = ((0 * 4 + g) ^ (fr & 7)) << 4;
    const int offA1 = ((1 * 4 + g) ^ (fr & 7)) << 4;

    // B: plane stride = one k-chunk of all N columns
    const size_t PS = (size_t)N_OUT * 16;        // 32 KB
    const uint8_t* gBt = Wqt + (size_t)(col0 + wn + fr) * 16 + (size_t)g * PS;

    for (int kb = 0; kb < KB4; kb += BKBY) {
        #pragma unroll
        for (int i = 0; i < 4; i++)
            load_lds16(gA + (size_t)(i * 32) * KB4 + kb, lA + i * 32 * BKBY);

        const uint8_t* bp = gBt + (size_t)(kb >> 4) * PS;
        v4i b0[4];
        #pragma unroll
        for (int ni = 0; ni < 4; ni++)           // kh=0 frags: overlap DMA drain
            b0[ni] = *(const v4i*)(bp + ni * 256);

        __syncthreads();

        v4i b1[4];
        #pragma unroll
        for (int ni = 0; ni < 4; ni++)           // kh=1 frags: overlap kh0 MFMAs
            b1[ni] = *(const v4i*)(bp + 4 * PS + ni * 256);

        #pragma unroll
        for (int kh = 0; kh < 2; kh++) {
            const int offA = kh ? offA1 : offA0;
            v8i a[4];
            #pragma unroll
            for (int mi = 0; mi < 4; mi++) {
                v4i lo = *(const v4i*)(&As[(wm + mi * 16 + fr) * BKBY] + offA);
                a[mi] = (v8i){lo.x, lo.y, lo.z, lo.w, 0, 0, 0, 0};
            }
            #pragma unroll
            for (int mi = 0; mi < 4; mi++) {
                #pragma unroll
                for (int ni = 0; ni < 4; ni++) {
                    v4i lb = kh ? b1[ni] : b0[ni];
                    v8i b = (v8i){lb.x, lb.y, lb.z, lb.w, 0, 0, 0, 0};
                    acc[mi][ni] = __builtin_amdgcn_mfma_scale_f32_16x16x128_f8f6f4(
                        a[mi], b, acc[mi][ni],
                        4 /*cbsz: A=fp4 e2m1*/, 4 /*blgp: B=fp4 e2m1*/,
                        0, 0x7F7F7F7F,   /* A scales = 1.0 */
                        0, 0x7F7F7F7F);  /* B scales = 1.0 */
                }
            }
        }
        __syncthreads();
    }

    // epilogue: C/D layout col=lane&15, row=(lane>>4)*4+reg
    const int ecol = lane & 15;
    const int erow = (lane >> 4) * 4;

    float bi[4], be[4];
    #pragma unroll
    for (int ni = 0; ni < 4; ni++) {
        int col = col0 + wn + ni * 16 + ecol;
        bi[ni] = bias[col];
        be[ni] = beta[col];
    }
    #pragma unroll
    for (int mi = 0; mi < 4; mi++) {
        int rbase = row0 + wm + mi * 16 + erow;
        float sc[4];
        #pragma unroll
        for (int r = 0; r < 4; r++) sc[r] = scale[rbase + r];
        #pragma unroll
        for (int ni = 0; ni < 4; ni++) {
            int col = col0 + wn + ni * 16 + ecol;
            float* op = out + (size_t)rbase * N_OUT + col;
            #pragma unroll
            for (int r = 0; r < 4; r++)
                op[(size_t)r * N_OUT] = (acc[mi][ni][r] * sc[r] + bi[ni]) * be[ni];
        }
    }
}

// ---------------------------------------------------------------------------
// Fallback (no workspace): correct but slow.
__global__ __launch_bounds__(256) void fallback_kernel(
    const float* __restrict__ in, const float* __restrict__ w,
    const float* __restrict__ bias, const float* __restrict__ gamma,
    const float* __restrict__ beta, float* __restrict__ out)
{
    __shared__ float s_sign[K_IN];
    __shared__ float sred[4];
    const int row = blockIdx.x;
    const int tid = threadIdx.x;
    float m = 0.f;
    for (int k = tid; k < K_IN; k += 256) {
        float x = in[(size_t)row * K_IN + k];
        m = fmaxf(m, fabsf(x));
        float s = (x > 0.f) ? 1.f : ((x < 0.f) ? -1.f : 0.f);
        s_sign[k] = s / gamma[k];
    }
    #pragma unroll
    for (int off = 32; off > 0; off >>= 1) m = fmaxf(m, __shfl_down(m, off));
    if ((tid & 63) == 0) sred[tid >> 6] = m;
    __syncthreads();
    float qs = fmaxf(fmaxf(sred[0], sred[1]), fmaxf(sred[2], sred[3]));
    for (int o = tid; o < N_OUT; o += 256) {
        const float* wr = w + (size_t)o * K_IN;
        float acc2 = 0.f;
        for (int k = 0; k < K_IN; k++) {
            float wv = wr[k];
            float ws_ = (wv > 0.f) ? 1.f : ((wv < 0.f) ? -1.f : 0.f);
            acc2 += s_sign[k] * ws_;
        }
        out[(size_t)row * N_OUT + o] = (acc2 * qs + bias[o]) * beta[o];
    }
}

// ---------------------------------------------------------------------------
extern "C" void kernel_launch(void* const* d_in, const int* in_sizes, int n_in,
                              void* d_out, int out_size, void* d_ws, size_t ws_size,
                              hipStream_t stream) {
    const float* input  = (const float*)d_in[0];
    const float* weight = (const float*)d_in[1];
    const float* bias   = (const float*)d_in[2];
    const float* gamma  = (const float*)d_in[3];
    const float* beta   = (const float*)d_in[4];
    float* out = (float*)d_out;

    const size_t aq_bytes = (size_t)M_ROWS * KB4;             // 8 MB
    const size_t wq_bytes = (size_t)N_OUT * KB4;              // 2 MB
    const size_t sc_bytes = (size_t)M_ROWS * sizeof(float);   // 32 KB

    if (ws_size >= aq_bytes + wq_bytes + sc_bytes) {
        uint8_t* aq    = (uint8_t*)d_ws;
        uint8_t* wqt   = (uint8_t*)d_ws + aq_bytes;
        float*   scale = (float*)((char*)d_ws + aq_bytes + wq_bytes);

        const int q_blocks = (M_ROWS + N_OUT) / 4;            // 2560 (4 waves/blk)
        quant_rows<<<q_blocks, 256, 0, stream>>>(
            input, weight, gamma, aq, wqt, scale);
        dim3 grid(M_ROWS / BM, N_OUT / BN);
        gemm_q<<<grid, 256, 0, stream>>>(aq, wqt, scale, bias, beta, out);
    } else {
        fallback_kernel<<<M_ROWS, 256, 0, stream>>>(input, weight, bias, gamma, beta, out);
    }
}